// Round 4
// baseline (683.891 us; speedup 1.0000x reference)
//
#include <hip/hip_runtime.h>
#include <hip/hip_bf16.h>

#define N_NODES 100000
#define N_EDGES 3200000
#define F_IN    128
#define HID     16
#define N_DRUGS 2000
#define NB      391   // ceil(N_NODES/256)

// ---------------- CSR build ----------------

__global__ void k_zero(int* __restrict__ cnt) {
    int i = blockIdx.x * blockDim.x + threadIdx.x;
    if (i < N_NODES) cnt[i] = 0;
}

__global__ void k_hist(const int* __restrict__ dst, int* __restrict__ cnt) {
    int e = blockIdx.x * blockDim.x + threadIdx.x;
    if (e < N_EDGES) atomicAdd(&cnt[dst[e]], 1);
}

__global__ void k_dinv(const int* __restrict__ cnt, float* __restrict__ dinv) {
    int i = blockIdx.x * blockDim.x + threadIdx.x;
    if (i < N_NODES) dinv[i] = rsqrtf((float)(cnt[i] + 1));  // +1 self loop
}

__global__ void k_scan1(const int* __restrict__ cnt, int* __restrict__ bs) {
    __shared__ int s[256];
    int t = threadIdx.x, i = blockIdx.x * 256 + t;
    s[t] = (i < N_NODES) ? cnt[i] : 0;
    __syncthreads();
    for (int off = 128; off > 0; off >>= 1) {
        if (t < off) s[t] += s[t + off];
        __syncthreads();
    }
    if (t == 0) bs[blockIdx.x] = s[0];
}

__global__ void k_scan2(const int* __restrict__ bs, int* __restrict__ boff) {
    __shared__ int s[512];
    int t = threadIdx.x;
    int v = (t < NB) ? bs[t] : 0;
    s[t] = v;
    __syncthreads();
    for (int off = 1; off < 512; off <<= 1) {
        int x = (t >= off) ? s[t - off] : 0;
        __syncthreads();
        s[t] += x;
        __syncthreads();
    }
    if (t < NB) boff[t] = s[t] - v;  // exclusive
}

__global__ void k_scan3(const int* __restrict__ cnt, const int* __restrict__ boff,
                        int* __restrict__ rowStart, int* __restrict__ rowNext) {
    __shared__ int s[256];
    int t = threadIdx.x, i = blockIdx.x * 256 + t;
    int v = (i < N_NODES) ? cnt[i] : 0;
    s[t] = v;
    __syncthreads();
    for (int off = 1; off < 256; off <<= 1) {
        int x = (t >= off) ? s[t - off] : 0;
        __syncthreads();
        s[t] += x;
        __syncthreads();
    }
    if (i < N_NODES) {
        int rs = boff[blockIdx.x] + s[t] - v;
        rowStart[i] = rs;
        rowNext[i]  = rs;
    }
}

__global__ void k_fill(const int* __restrict__ src, const int* __restrict__ dst,
                       int* __restrict__ rowNext, int* __restrict__ csr_src) {
    int e = blockIdx.x * blockDim.x + threadIdx.x;
    if (e < N_EDGES) {
        int d = dst[e];
        int idx = atomicAdd(&rowNext[d], 1);
        csr_src[idx] = src[e];
    }
}

// ---------------- hw = x @ W1 (thread per node, W via scalar loads) ----------------

__global__ void k_xw1(const float* __restrict__ x, const float* __restrict__ W1,
                      float* __restrict__ hw) {
    int node = blockIdx.x * blockDim.x + threadIdx.x;
    if (node >= N_NODES) return;
    float acc[16];
#pragma unroll
    for (int h = 0; h < 16; ++h) acc[h] = 0.0f;
    const float4* xr = (const float4*)(x + (long)node * F_IN);
#pragma unroll 2
    for (int k0 = 0; k0 < 32; ++k0) {
        float4 xv = xr[k0];
        float xj[4] = {xv.x, xv.y, xv.z, xv.w};
#pragma unroll
        for (int j = 0; j < 4; ++j) {
            int k = k0 * 4 + j;
#pragma unroll
            for (int h = 0; h < 16; ++h) acc[h] += xj[j] * W1[k * 16 + h];
        }
    }
    float4* o = (float4*)(hw + node * HID);
#pragma unroll
    for (int q = 0; q < 4; ++q)
        o[q] = make_float4(acc[q * 4], acc[q * 4 + 1], acc[q * 4 + 2], acc[q * 4 + 3]);
}

// ---------------- gather: agg[v] = b + dv*(dv*hw[v] + sum dinv[s]*hw[s]) ----------------

__global__ void k_gather(const int* __restrict__ rowStart, const int* __restrict__ cnt,
                         const int* __restrict__ csr_src, const float* __restrict__ dinv,
                         const float* __restrict__ hw, const float* __restrict__ b,
                         float* __restrict__ agg) {
    int t = threadIdx.x;                 // 256 = 16 nodes x 16 feats
    int node = blockIdx.x * 16 + (t >> 4);
    int f = t & 15;
    if (node >= N_NODES) return;
    float dv = dinv[node];
    float acc = dv * hw[node * HID + f];  // self-loop message (pre-dv factor)
    int row = rowStart[node], n = cnt[node];
    int j = 0;
    for (; j + 1 < n; j += 2) {
        int s0 = csr_src[row + j], s1 = csr_src[row + j + 1];
        acc += dinv[s0] * hw[s0 * HID + f] + dinv[s1] * hw[s1 * HID + f];
    }
    if (j < n) {
        int s0 = csr_src[row + j];
        acc += dinv[s0] * hw[s0 * HID + f];
    }
    agg[node * HID + f] = dv * acc + b[f];
}

// ---------------- hw2 = relu(agg) @ W2 ----------------

__global__ void k_hw2(const float* __restrict__ agg, const float* __restrict__ W2,
                      float* __restrict__ hw2) {
    __shared__ float w2s[16][17];
    int tid = threadIdx.x;  // 256
    w2s[tid >> 4][tid & 15] = W2[tid];
    __syncthreads();
    int gid = blockIdx.x * 256 + tid;
    if (gid >= N_NODES * HID) return;
    int node = gid >> 4, f = gid & 15;
    float acc = 0.0f;
#pragma unroll
    for (int k = 0; k < 16; ++k) {
        float hv = agg[node * HID + k];
        hv = hv > 0.0f ? hv : 0.0f;
        acc += hv * w2s[k][f];
    }
    hw2[gid] = acc;
}

// ---------------- t = hd @ predictor ----------------

__global__ void k_t(const float* __restrict__ agg, const float* __restrict__ pred,
                    float* __restrict__ t) {
    __shared__ float ps[256];
    int tid = threadIdx.x;
    ps[tid] = pred[tid];
    __syncthreads();
    int gid = blockIdx.x * 256 + tid;
    if (gid >= N_DRUGS * HID) return;
    int i = gid >> 4, k = gid & 15;
    float acc = 0.0f;
#pragma unroll
    for (int m = 0; m < 16; ++m) acc += agg[i * HID + m] * ps[m * 16 + k];
    t[gid] = acc;
}

// ---------------- out[i][j] = dot(t[i], hd[j]) ----------------

__global__ void k_out(const float* __restrict__ t, const float* __restrict__ agg,
                      float* __restrict__ out) {
    __shared__ float ts[16][17], hs[16][17];
    int tid = threadIdx.x;  // 256
    int li = tid >> 4, lj = tid & 15;
    int i0 = blockIdx.y * 16, j0 = blockIdx.x * 16;
    ts[li][lj] = t[(i0 + li) * HID + lj];
    hs[li][lj] = agg[(j0 + li) * HID + lj];
    __syncthreads();
    float acc = 0.0f;
#pragma unroll
    for (int k = 0; k < 16; ++k) acc += ts[li][k] * hs[lj][k];
    out[(long)(i0 + li) * N_DRUGS + (j0 + lj)] = acc;
}

extern "C" void kernel_launch(void* const* d_in, const int* in_sizes, int n_in,
                              void* d_out, int out_size, void* d_ws, size_t ws_size,
                              hipStream_t stream) {
    const float* x    = (const float*)d_in[0];
    const int*   ei   = (const int*)d_in[1];
    const float* W1   = (const float*)d_in[2];
    const float* b1   = (const float*)d_in[3];
    const float* W2   = (const float*)d_in[4];
    const float* b2   = (const float*)d_in[5];
    const float* pred = (const float*)d_in[6];
    float* out = (float*)d_out;

    const int* src = ei;             // edge_index[0]
    const int* dst = ei + N_EDGES;   // edge_index[1]

    char* w = (char*)d_ws;
    int*   cnt      = (int*)w;                 w += (size_t)N_NODES * 4;
    int*   rowStart = (int*)w;                 w += (size_t)N_NODES * 4;
    int*   rowNext  = (int*)w;                 w += (size_t)N_NODES * 4;
    float* dinv     = (float*)w;               w += (size_t)N_NODES * 4;
    int*   bsum     = (int*)w;                 w += 512 * 4;
    int*   boff     = (int*)w;                 w += 512 * 4;
    int*   csr_src  = (int*)w;                 w += (size_t)N_EDGES * 4;
    float* hw       = (float*)w;               w += (size_t)N_NODES * HID * 4;
    float* agg      = (float*)w;               w += (size_t)N_NODES * HID * 4;
    float* tbuf     = (float*)w;               w += (size_t)N_DRUGS * HID * 4;

    const int B = 256;
    const int EB = (N_EDGES + B - 1) / B;

    // CSR build + dinv
    k_zero<<<NB, B, 0, stream>>>(cnt);
    k_hist<<<EB, B, 0, stream>>>(dst, cnt);
    k_dinv<<<NB, B, 0, stream>>>(cnt, dinv);
    k_scan1<<<NB, B, 0, stream>>>(cnt, bsum);
    k_scan2<<<1, 512, 0, stream>>>(bsum, boff);
    k_scan3<<<NB, B, 0, stream>>>(cnt, boff, rowStart, rowNext);
    k_fill<<<EB, B, 0, stream>>>(src, dst, rowNext, csr_src);

    // layer 1
    k_xw1<<<NB, B, 0, stream>>>(x, W1, hw);
    k_gather<<<(N_NODES + 15) / 16, B, 0, stream>>>(rowStart, cnt, csr_src, dinv, hw, b1, agg);

    // layer 2
    k_hw2<<<(N_NODES * HID + B - 1) / B, B, 0, stream>>>(agg, W2, hw);
    k_gather<<<(N_NODES + 15) / 16, B, 0, stream>>>(rowStart, cnt, csr_src, dinv, hw, b2, agg);

    // readout
    k_t<<<(N_DRUGS * HID + B - 1) / B, B, 0, stream>>>(agg, pred, tbuf);
    dim3 og(N_DRUGS / 16, N_DRUGS / 16);
    k_out<<<og, B, 0, stream>>>(tbuf, agg, out);
}